// Round 6
// baseline (524.980 us; speedup 1.0000x reference)
//
#include <hip/hip_runtime.h>
#include <stdint.h>

#define S_LEN 2048
#define BATCH 2
#define NH 32
#define NKV 8
#define HD 128
#define NE 6144   // extracted columns of zxbcdt: x(1024) | B(1024) | C(4096)

typedef __attribute__((ext_vector_type(8))) short short8;
typedef __attribute__((ext_vector_type(4))) float floatx4;

__device__ __forceinline__ unsigned short f2bf(float f) {
    union { float f; uint32_t u; } v; v.f = f;
    uint32_t u = v.u;
    u += 0x7FFFu + ((u >> 16) & 1u);   // RTN-even (inputs are finite)
    return (unsigned short)(u >> 16);
}
__device__ __forceinline__ float bf2f(unsigned short h) {
    union { uint32_t u; float f; } v; v.u = ((uint32_t)h) << 16;
    return v.f;
}
__device__ __forceinline__ uint32_t cvt_pk_bf16(float lo, float hi) {
    uint32_t r;
    asm("v_cvt_pk_bf16_f32 %0, %1, %2" : "=v"(r) : "v"(lo), "v"(hi));
    return r;
}

// ---------------- cast fp32 -> bf16, 4 elems/thread ----------------
__global__ void cast_f32_bf16(const float* __restrict__ in,
                              unsigned short* __restrict__ out, int n4) {
    int i = blockIdx.x * blockDim.x + threadIdx.x;
    if (i >= n4) return;
    float4 f = reinterpret_cast<const float4*>(in)[i];
    ushort4 o;
    o.x = f2bf(f.x); o.y = f2bf(f.y); o.z = f2bf(f.z); o.w = f2bf(f.w);
    reinterpret_cast<ushort4*>(out)[i] = o;
}

// ---------------- 256x128 GEMM engine, 1-barrier/K-tile (T2+T4+T5) ----------------
// C[M,N] = A[M,K] * Bt[N,K]^T. 512 threads = 8 waves (4M x 2N), per-wave 64x64,
// BK=64, TRIPLE-buffered LDS (A 3x32KB + B 3x16KB = 144 KB, 1 block/CU).
// R5 postmortem: per-phase lockstep barriers serialized LDS/VALU/MFMA pipes
// (wall ~3150 cyc/tile vs MFMA floor ~1030). Triple buffering removes the
// read-vs-overwrite hazard that required them: STAGE(t+2) targets the buffer
// holding t-1, whose ds_reads completed before each wave's last t-1 MFMA
// (compiler lgkmcnt), which preceded the top-of-t barrier. -> ONE
// vmcnt(6)+s_barrier per K-tile; waves drift within a tile so one wave's
// ds_reads overlap its SIMD-mate's MFMAs (setprio arbitrates).
// T2 swizzle (R4-verified): LDS linear for gload_lds; global SOURCE chunk
// pre-swizzled c8s=(l&7)^((l>>3)&7); ds_read XORs back c8=k8^(row&7); phase-2
// chunk (k8+4) is just byte-offset XOR 64.
// XCD mapping: 2D rectangles per XCD (args) so each XCD re-fetches only its
// own A-rows and B-cols (cuts the 25MB-B x8-XCD duplication seen in R5).
template <int OUT_BF16>
__global__ void __launch_bounds__(512, 2)
gemm_256x128(const unsigned short* __restrict__ A, const unsigned short* __restrict__ Bt,
             void* __restrict__ Cv, int M, int N, int K,
             int mcMask, int mcLog2, int nchxLog2, int NC) {
    __shared__ unsigned short As[3][256 * 64];   // 96 KB
    __shared__ unsigned short Bs[3][128 * 64];   // 48 KB
    const int tid  = threadIdx.x;
    const int w    = tid >> 6;
    const int lane = tid & 63;
    const int quad = lane >> 4;
    const int l16  = lane & 15;
    const int wm   = w >> 1, wn = w & 1;     // 4M x 2N wave grid

    // XCD 2D rectangle mapping: xcd = lin%8 owns an (MC x NC) tile rectangle
    const int lin = blockIdx.y * gridDim.x + blockIdx.x;
    const int xcd = lin & 7, idx = lin >> 3;
    const int im  = idx & mcMask, inn = idx >> mcLog2;
    const int mc  = xcd >> nchxLog2, nc = xcd & ((1 << nchxLog2) - 1);
    const int m0  = ((mc << mcLog2) | im) << 8;
    const int n0  = (nc * NC + inn) << 7;

    floatx4 acc[4][4];
#pragma unroll
    for (int i = 0; i < 4; i++)
#pragma unroll
        for (int j = 0; j < 4; j++) acc[i][j] = {0.f, 0.f, 0.f, 0.f};

    // precomputed per-lane LDS frag offsets (elements); phase2 = offset ^ 32
    int offA[4], offB[4];
#pragma unroll
    for (int mi = 0; mi < 4; ++mi) {
        const int row = wm * 64 + mi * 16 + l16;
        offA[mi] = row * 64 + ((quad ^ (row & 7)) * 8);
    }
#pragma unroll
    for (int ni = 0; ni < 4; ++ni) {
        const int row = wn * 64 + ni * 16 + l16;
        offB[ni] = row * 64 + ((quad ^ (row & 7)) * 8);
    }

    // staging addresses: wave w owns A rows [w*32,w*32+32) (4 loads) and
    // B rows [w*16,w*16+16) (2 loads); each gload_lds covers 8 rows.
    const int l8  = lane >> 3;
    const int c8s = (lane & 7) ^ ((lane >> 3) & 7);   // inverse swizzle on source
    const unsigned short* apA = A  + (size_t)(m0 + w * 32 + l8) * K + c8s * 8;
    const unsigned short* apB = Bt + (size_t)(n0 + w * 16 + l8) * K + c8s * 8;

#define GLD(src, dst) __builtin_amdgcn_global_load_lds(                        \
    (const __attribute__((address_space(1))) void*)(src),                      \
    (__attribute__((address_space(3))) void*)(dst), 16, 0, 0)

#define STAGE6(Adst, Bdst, t) do {      /* 4 A loads + 2 B loads */            \
    unsigned short* dA = (Adst) + w * 32 * 64;                                 \
    const unsigned short* sA = apA + (size_t)(t) * 64;                         \
    GLD(sA,                   dA);                                             \
    GLD(sA + (size_t)8  * K,  dA + 8  * 64);                                   \
    GLD(sA + (size_t)16 * K,  dA + 16 * 64);                                   \
    GLD(sA + (size_t)24 * K,  dA + 24 * 64);                                   \
    unsigned short* dB = (Bdst) + w * 16 * 64;                                 \
    const unsigned short* sB = apB + (size_t)(t) * 64;                         \
    GLD(sB,                   dB);                                             \
    GLD(sB + (size_t)8 * K,   dB + 8 * 64);                                    \
} while (0)

    // rotating buffer pointers: cur = tile t, nxt = t+1, fr = free (holds t-1)
    unsigned short *Acur = &As[0][0], *Anxt = &As[1][0], *Afr = &As[2][0];
    unsigned short *Bcur = &Bs[0][0], *Bnxt = &Bs[1][0], *Bfr = &Bs[2][0];

    // prologue: stage tiles 0 and 1
    STAGE6(Acur, Bcur, 0);
    STAGE6(Anxt, Bnxt, 1);

    const int NT = K >> 6;

#pragma unroll 1
    for (int t = 0; t < NT; ++t) {
        // single sync point per K-tile: own tile-t loads landed (counted),
        // then barrier publishes them block-wide + certifies t-1 reads done.
        if (t < NT - 1) { asm volatile("s_waitcnt vmcnt(6)" ::: "memory"); }
        else            { asm volatile("s_waitcnt vmcnt(0)" ::: "memory"); }
        __builtin_amdgcn_s_barrier();
        asm volatile("" ::: "memory");

        if (t + 2 < NT) { STAGE6(Afr, Bfr, t + 2); }   // into t-1's buffer

        short8 a0[4], b0[4], a1[4], b1[4];
#pragma unroll
        for (int mi = 0; mi < 4; ++mi)
            a0[mi] = *reinterpret_cast<const short8*>(Acur + offA[mi]);
#pragma unroll
        for (int ni = 0; ni < 4; ++ni)
            b0[ni] = *reinterpret_cast<const short8*>(Bcur + offB[ni]);
        __builtin_amdgcn_s_setprio(1);
#pragma unroll
        for (int mi = 0; mi < 4; ++mi)
#pragma unroll
            for (int ni = 0; ni < 4; ++ni)
                acc[mi][ni] = __builtin_amdgcn_mfma_f32_16x16x32_bf16(a0[mi], b0[ni], acc[mi][ni], 0, 0, 0);
        __builtin_amdgcn_s_setprio(0);

#pragma unroll
        for (int mi = 0; mi < 4; ++mi)
            a1[mi] = *reinterpret_cast<const short8*>(Acur + (offA[mi] ^ 32));
#pragma unroll
        for (int ni = 0; ni < 4; ++ni)
            b1[ni] = *reinterpret_cast<const short8*>(Bcur + (offB[ni] ^ 32));
        __builtin_amdgcn_s_setprio(1);
#pragma unroll
        for (int mi = 0; mi < 4; ++mi)
#pragma unroll
            for (int ni = 0; ni < 4; ++ni)
                acc[mi][ni] = __builtin_amdgcn_mfma_f32_16x16x32_bf16(a1[mi], b1[ni], acc[mi][ni], 0, 0, 0);
        __builtin_amdgcn_s_setprio(0);

        // rotate buffers
        unsigned short* ta = Acur; Acur = Anxt; Anxt = Afr; Afr = ta;
        unsigned short* tb = Bcur; Bcur = Bnxt; Bnxt = Bfr; Bfr = tb;
    }
#undef STAGE6
#undef GLD

    // ---- epilogue ----
#pragma unroll
    for (int mi = 0; mi < 4; ++mi)
#pragma unroll
        for (int ni = 0; ni < 4; ++ni) {
            const int row = m0 + wm * 64 + mi * 16 + quad * 4;
            const int col = n0 + wn * 64 + ni * 16 + l16;
#pragma unroll
            for (int r = 0; r < 4; ++r) {
                float vv = acc[mi][ni][r];
                if (OUT_BF16)
                    ((unsigned short*)Cv)[(size_t)(row + r) * N + col] = f2bf(vv);
                else
                    ((float*)Cv)[(size_t)(row + r) * N + col] = vv;
            }
        }
}

// ---------------- RoPE + split/reshape ----------------
// Z: [4096 tokens][6144] bf16. Q[B,NH,S,HD] (pre-scaled by log2e/sqrt(128)),
// K[B,NKV,S,HD], Vt[B,NKV,HD,S] with s-within-64 PERMUTED to pair order
// (matches attn's pair-packed P layout; P,V contracted over same permuted k).
#define QSCALE 0.12748539509360f   // log2(e) / sqrt(128)
__global__ void rope_split(const unsigned short* __restrict__ Z,
                           unsigned short* __restrict__ Q,
                           unsigned short* __restrict__ Kb,
                           unsigned short* __restrict__ Vt) {
    const int PER_TOK = 2048 + 512 + 1024;  // q-pairs + k-pairs + v-elems
    int idx = blockIdx.x * blockDim.x + threadIdx.x;
    if (idx >= BATCH * S_LEN * PER_TOK) return;
    int t = idx / PER_TOK;
    int r = idx - t * PER_TOK;
    int b = t / S_LEN, s = t - b * S_LEN;
    const unsigned short* z = Z + (size_t)t * NE;
    if (r < 2048) {                 // q pair: C section
        int h = r >> 6, j = r & 63;
        float x0 = bf2f(z[2048 + h * 128 + j]);
        float x1 = bf2f(z[2048 + h * 128 + j + 64]);
        float inv = exp2f((float)j * -0.20762050593f);   // 10000^(-j/64)
        float c, sn; sincosf((float)s * inv, &sn, &c);
        size_t base = ((size_t)(b * NH + h) * S_LEN + s) * HD;
        Q[base + j]      = f2bf((x0 * c - x1 * sn) * QSCALE);
        Q[base + j + 64] = f2bf((x1 * c + x0 * sn) * QSCALE);
    } else if (r < 2560) {          // k pair: B section
        int rr = r - 2048; int kh = rr >> 6, j = rr & 63;
        float x0 = bf2f(z[1024 + kh * 128 + j]);
        float x1 = bf2f(z[1024 + kh * 128 + j + 64]);
        float inv = exp2f((float)j * -0.20762050593f);
        float c, sn; sincosf((float)s * inv, &sn, &c);
        size_t base = ((size_t)(b * NKV + kh) * S_LEN + s) * HD;
        Kb[base + j]      = f2bf(x0 * c - x1 * sn);
        Kb[base + j + 64] = f2bf(x1 * c + x0 * sn);
    } else {                        // v elem: x section, transposed+permuted store
        int m = r - 2560; int kh = m >> 7, d = m & 127;
        int k = s & 63;
        int kp = (k & 32) + ((k & 15) << 1) + ((k >> 4) & 1);
        int sp = (s & ~63) | kp;
        Vt[((size_t)(b * NKV + kh) * HD + d) * S_LEN + sp] = z[m];
    }
}

// ---------------- Flash attention v2 (causal, GQA 4:1) ----------------
// (unchanged: single-buffered LDS, 4 blocks/CU, pair-packed P via cvt_pk,
// diagonal-tile split, setprio around MFMA.)
template <bool DIAG>
__device__ __forceinline__ void attn_tile(
    const short8 (&qf)[4], floatx4 (&oacc)[8], float (&lsum)[4],
    const unsigned short* __restrict__ Ks, const unsigned short* __restrict__ Vs,
    unsigned short* __restrict__ pw, int w, int quad, int l16) {
    const int e = l16 & 7;

    // ---- QK^T: 4 n-tiles x 4 k-chunks ----
    floatx4 sacc[4];
#pragma unroll
    for (int nb = 0; nb < 4; nb++) sacc[nb] = {0.f, 0.f, 0.f, 0.f};
    __builtin_amdgcn_s_setprio(1);
#pragma unroll
    for (int ks = 0; ks < 4; ++ks) {
#pragma unroll
        for (int nb = 0; nb < 4; ++nb) {
            const int srow = nb * 16 + l16;
            const int pc = (ks * 4 + quad) ^ e;
            short8 kf = *reinterpret_cast<const short8*>(Ks + srow * 128 + pc * 8);
            sacc[nb] = __builtin_amdgcn_mfma_f32_16x16x32_bf16(qf[ks], kf, sacc[nb], 0, 0, 0);
        }
    }
    __builtin_amdgcn_s_setprio(0);

    // ---- exp2 (+ causal mask only on diagonal tile) ----
    float pv[4][4];
#pragma unroll
    for (int nb = 0; nb < 4; ++nb)
#pragma unroll
        for (int r = 0; r < 4; ++r) {
            float p = exp2f(sacc[nb][r]);
            if (DIAG)
                p = (nb * 16 + l16 <= w * 16 + quad * 4 + r) ? p : 0.0f;
            pv[nb][r] = p;
            lsum[r] += p;
        }

    // ---- P store: pair-packed b32, XOR chunk swizzle (2-way, free) ----
    const int row0 = quad * 4;
    const int sub = l16 >> 2, off = (l16 & 3) * 2;
#pragma unroll
    for (int r = 0; r < 4; ++r) {
        const int rowe = (row0 + r) & 7;
#pragma unroll
        for (int g = 0; g < 2; ++g) {
            uint32_t pk = cvt_pk_bf16(pv[g * 2][r], pv[g * 2 + 1][r]);
            const int chunk = (g * 4 + sub) ^ rowe;
            *reinterpret_cast<uint32_t*>(pw + (row0 + r) * 64 + chunk * 8 + off) = pk;
        }
    }

    // ---- PV: 2 k-chunks x 8 d-tiles (wave-private Ps, no barrier) ----
    __builtin_amdgcn_s_setprio(1);
#pragma unroll
    for (int kv_sub = 0; kv_sub < 2; ++kv_sub) {
        const int pcP = (kv_sub * 4 + quad) ^ e;
        short8 pf = *reinterpret_cast<const short8*>(pw + l16 * 64 + pcP * 8);
#pragma unroll
        for (int dt = 0; dt < 8; ++dt) {
            const int drow = dt * 16 + l16;
            const int pcV = (kv_sub * 4 + quad) ^ e;
            short8 vf = *reinterpret_cast<const short8*>(Vs + drow * 64 + pcV * 8);
            oacc[dt] = __builtin_amdgcn_mfma_f32_16x16x32_bf16(pf, vf, oacc[dt], 0, 0, 0);
        }
    }
    __builtin_amdgcn_s_setprio(0);
}

__global__ void __launch_bounds__(256, 4)
attn_kernel(const unsigned short* __restrict__ Q,
            const unsigned short* __restrict__ Kb,
            const unsigned short* __restrict__ Vt,
            unsigned short* __restrict__ Ob) {
    __shared__ unsigned short Ks[64 * 128];   // [s][d] swizzled, 16 KB
    __shared__ unsigned short Vs[128 * 64];   // [d][s'] swizzled, 16 KB
    __shared__ unsigned short Ps[4][16 * 64]; // per-wave P, swizzled, 8 KB
    const int tid  = threadIdx.x;
    const int w    = tid >> 6;
    const int lane = tid & 63;
    const int quad = lane >> 4;
    const int l16  = lane & 15;
    const int blk = blockIdx.x;
    const int qt = 31 - (blk >> 6);      // heavy blocks dispatch first
    const int bh = blk & 63;
    const int h = bh & 31, b = bh >> 5;
    const int kvh = h >> 2;
    const int qw0 = qt * 64 + w * 16;

    const unsigned short* Qbase = Q  + ((size_t)(b * NH  + h)   * S_LEN) * HD;
    const unsigned short* Kbase = Kb + ((size_t)(b * NKV + kvh) * S_LEN) * HD;
    const unsigned short* Vbase = Vt + ((size_t)(b * NKV + kvh) * HD) * S_LEN;

    short8 qf[4];
    {
        const unsigned short* qrow = Qbase + (size_t)(qw0 + l16) * HD + quad * 8;
#pragma unroll
        for (int ks = 0; ks < 4; ++ks)
            qf[ks] = *reinterpret_cast<const short8*>(qrow + ks * 32);
    }

    floatx4 oacc[8];
#pragma unroll
    for (int i = 0; i < 8; i++) oacc[i] = {0.f, 0.f, 0.f, 0.f};
    float lsum[4] = {0.f, 0.f, 0.f, 0.f};

    // per-lane staging pointers, advanced one KV tile per STAGE
    const unsigned short* kp[4];
    const unsigned short* vp[4];
#pragma unroll
    for (int c = 0; c < 4; ++c) {
        const int bI = w * 4 + c;                       // wave-uniform block idx
        const int krow = bI * 4 + (lane >> 4);          // 0..63
        kp[c] = Kbase + (size_t)krow * HD + ((lane & 15) ^ (krow & 7)) * 8;
        const int drow = bI * 8 + (lane >> 3);          // 0..127
        vp[c] = Vbase + (size_t)drow * S_LEN + ((lane & 7) ^ (drow & 7)) * 8;
    }

#define STAGE() do {                                                           \
    _Pragma("unroll")                                                          \
    for (int c = 0; c < 4; ++c) {                                              \
        const int bI = w * 4 + c;                                              \
        __builtin_amdgcn_global_load_lds(                                      \
            (const __attribute__((address_space(1))) void*)kp[c],              \
            (__attribute__((address_space(3))) void*)(Ks + bI * 512), 16, 0, 0);\
        __builtin_amdgcn_global_load_lds(                                      \
            (const __attribute__((address_space(1))) void*)vp[c],              \
            (__attribute__((address_space(3))) void*)(Vs + bI * 512), 16, 0, 0);\
        kp[c] += 64 * HD; vp[c] += 64;                                         \
    }                                                                          \
} while (0)

    unsigned short* pw = &Ps[w][0];

    // main loop: tiles strictly below the diagonal block -> no masking
    for (int t = 0; t < qt; ++t) {
        __syncthreads();   // previous-iter LDS reads done before overwrite
        STAGE();
        __syncthreads();   // staging complete
        attn_tile<false>(qf, oacc, lsum, Ks, Vs, pw, w, quad, l16);
    }
    // diagonal tile: masked
    __syncthreads();
    STAGE();
    __syncthreads();
    attn_tile<true>(qf, oacc, lsum, Ks, Vs, pw, w, quad, l16);
#undef STAGE

    // ---- final row-sum reduce + write ----
    float linv[4];
#pragma unroll
    for (int r = 0; r < 4; ++r) {
        float s = lsum[r];
#pragma unroll
        for (int off = 1; off < 16; off <<= 1) s += __shfl_xor(s, off);
        linv[r] = 1.0f / s;
    }
#pragma unroll
    for (int dt = 0; dt < 8; ++dt) {
        const int d = dt * 16 + l16;
#pragma unroll
        for (int r = 0; r < 4; ++r) {
            const int row = qw0 + quad * 4 + r;
            Ob[((size_t)(b * S_LEN + row)) * 4096 + h * 128 + d] = f2bf(oacc[dt][r] * linv[r]);
        }
    }
}

extern "C" void kernel_launch(void* const* d_in, const int* in_sizes, int n_in,
                              void* d_out, int out_size, void* d_ws, size_t ws_size,
                              hipStream_t stream) {
    const float* u     = (const float*)d_in[0];
    const float* W_in  = (const float*)d_in[1];
    const float* W_out = (const float*)d_in[2];
    float* out = (float*)d_out;

    char* ws = (char*)d_ws;
    unsigned short* u_bf    = (unsigned short*)(ws);                    //  16,777,216 B
    unsigned short* win_bf  = (unsigned short*)(ws + 16777216);         //  25,165,824 B
    unsigned short* wout_bf = (unsigned short*)(ws + 41943040);         //  16,777,216 B
    unsigned short* Z       = (unsigned short*)(ws + 58720256);         //  50,331,648 B
    unsigned short* Qb      = (unsigned short*)(ws + 109051904);        //  33,554,432 B
    unsigned short* Kv      = (unsigned short*)(ws + 142606336);        //   8,388,608 B
    unsigned short* Vt      = (unsigned short*)(ws + 150994944);        //   8,388,608 B
    unsigned short* Ob      = (unsigned short*)(ws + 159383552);        //  33,554,432 B
    // total: 192,937,984 B

    {   // casts
        int n4 = (2 * 2048 * 2048) / 4;
        cast_f32_bf16<<<(n4 + 255) / 256, 256, 0, stream>>>(u, u_bf, n4);
        n4 = (6144 * 2048) / 4;   // only the used rows [4096,10240) of W_in
        cast_f32_bf16<<<(n4 + 255) / 256, 256, 0, stream>>>(W_in + (size_t)4096 * 2048, win_bf, n4);
        n4 = (2048 * 4096) / 4;
        cast_f32_bf16<<<(n4 + 255) / 256, 256, 0, stream>>>(W_out, wout_bf, n4);
    }
    {   // GEMM1: Z[4096,6144] = u_bf[4096,2048] @ win_bf[6144,2048]^T
        // 48 x 16 = 768 blocks = 3 exact rounds; XCD rects 8m x 12n
        dim3 g(6144 / 128, 4096 / 256);
        gemm_256x128<1><<<g, 512, 0, stream>>>(u_bf, win_bf, Z, 4096, 6144, 2048,
                                               7, 3, 2, 12);
    }
    {   // RoPE + split (V stored s-within-64 pair-permuted)
        int n = BATCH * S_LEN * 3584;
        rope_split<<<(n + 255) / 256, 256, 0, stream>>>(Z, Qb, Kv, Vt);
    }
    // attention: grid = (S/64) * B * NH, heavy q-tiles first
    attn_kernel<<<BATCH * NH * (S_LEN / 64), 256, 0, stream>>>(Qb, Kv, Vt, Ob);
    {   // GEMM2: out[4096,2048] = Ob[4096,4096] @ wout_bf[2048,4096]^T (fp32 store)
        // 16 x 16 = 256 blocks = 1 exact round; XCD rects 4m x 8n
        dim3 g(2048 / 128, 4096 / 256);
        gemm_256x128<0><<<g, 512, 0, stream>>>(Ob, wout_bf, out, 4096, 2048, 4096,
                                               3, 2, 1, 8);
    }
}